// Round 14
// baseline (548.325 us; speedup 1.0000x reference)
//
#include <hip/hip_runtime.h>

typedef __attribute__((ext_vector_type(8))) short short8;
typedef __attribute__((ext_vector_type(4))) float f32x4;
typedef unsigned int u32;

#define CIN   128
#define COUT  256
#define H     112
#define W     112
#define OH    110
#define OW    110
#define KHW   9
#define TH    8
#define TW    32
#define IWW   34              // TW+2
#define NPIX  340             // 10*34
#define XB    (NPIX*8*16)     // 43520 B: x half-tile, 2720 16B slots
#define WB    16384           // w tap-half: 128 cout * 8 slots * 16B
#define ROWB  (IWW*128)       // 4352: LDS bytes per x row

__device__ __forceinline__ short f2b(float f) {
  unsigned u = __builtin_bit_cast(unsigned, f);
  unsigned r = (u + 0x7FFFu + ((u >> 16) & 1u)) >> 16;  // RNE
  return (short)r;
}

__device__ __forceinline__ void gload16(const void* g, void* l) {
  __builtin_amdgcn_global_load_lds(
      (const __attribute__((address_space(1))) u32*)g,
      (__attribute__((address_space(3))) u32*)l, 16, 0, 0);
}

// x LDS (R13): byte(p,G) = p*128 + ((G ^ (ix&7))<<4), ix = p mod 34 —
// swizzle key is row-invariant, so row/kh walks are pure +4352 immediates.
// DMA keeps linear dest; swizzle pre-applied on per-lane GLOBAL source (m173).
// w LDS: byte = c*128 + ((G^(c&7))<<4), same source-swizzle scheme.
// R14: kh-window B reuse (R12 idea x R13 addressing). Loop (hh,s,kw,kh):
// read 12-frag B-window (6 rows x 2 cg, 2 bases + imm) once per (s,kw),
// reuse across 3 kh taps -> B-reads/wave/half 144->72 (-33% LDS traffic).
// w staged per (s,kw,kh) stage (36 stages; 2x per half; L2-resident).
// Register fit: win 48 + a 16 + addr ~30 < 124 free VGPRs (R12's spill fix).

template<bool XT, bool WT>
__global__ __launch_bounds__(256, 2)
void conv_main(const float* __restrict__ x, const float* __restrict__ wgt,
               const short* __restrict__ wt, const short* __restrict__ xt,
               const short* __restrict__ zp, float* __restrict__ out) {
  __shared__ __align__(16) char smem[XB + 2*WB];   // 76288 B -> 2 blocks/CU
  char* sx = smem;
  char* sw = smem + XB;

  const int tid = threadIdx.x;

  // XCD-chunked bijective swizzle (3584 % 8 == 0)
  const int nb  = gridDim.x;
  const int swz = (blockIdx.x & 7) * (nb >> 3) + (blockIdx.x >> 3);
  const int b    = swz / 112;            // 2 cblk * 4 tw * 14 th
  const int rem  = swz - b * 112;
  const int cblk = rem / 56;
  const int rem2 = rem - cblk * 56;
  const int t_w  = rem2 / 14;
  const int t_h  = rem2 - t_w * 14;
  const int h0 = t_h * TH, w0 = t_w * TW;

  auto stage_x = [&](int hh) {
    if (XT) {
      const short* xtb = xt + (size_t)b * (H*W*CIN);
      #pragma unroll
      for (int it = 0; it < 11; ++it) {
        int u = it*256 + tid;            // slot index, 2720 total
        if (u < 8*NPIX) {                // prefix-masked tail only: safe
          int p = u >> 3;                // pixel 0..339
          int iy = p / IWW, ix = p - iy * IWW;
          int Geff = (u & 7) ^ (ix & 7); // pre-swizzled source fragment
          int gy = h0 + iy, gx = w0 + ix;
          const short* src = (gy < H && gx < W)
              ? xtb + ((size_t)gy*W + gx)*CIN + hh*64 + Geff*8
              : zp;                      // OOB -> zero page (per-lane src ok)
          gload16(src, sx + u*16);
        }
      }
    } else {
      const float* xh = x + (size_t)b * CIN * (H*W) + (size_t)(hh*64) * (H*W);
      for (int u = tid; u < 8 * NPIX; u += 256) {
        int G = u / NPIX, p = u - G * NPIX;
        int iy = p / IWW, ix = p - iy * IWW;
        int gy = h0 + iy, gx = w0 + ix;
        short8 v = {0,0,0,0,0,0,0,0};
        if (gy < H && gx < W) {
          const float* s = xh + (size_t)(G*8) * (H*W) + gy * W + gx;
          #pragma unroll
          for (int j = 0; j < 8; ++j) v[j] = f2b(s[j * (H*W)]);
        }
        *(short8*)(sx + p*128 + ((G ^ (ix & 7)) << 4)) = v;
      }
    }
  };

  auto stage_w = [&](int tap, int hh, int buf) {
    if (WT) {
      const short* base = wt + (size_t)tap * (COUT*CIN)
                             + (size_t)(cblk*128) * CIN + hh * 64;
      #pragma unroll
      for (int it = 0; it < 4; ++it) {
        int slot = it * 256 + tid;            // 1024 slots of 16B
        int c = slot >> 3, gsw = (slot & 7) ^ (c & 7);
        gload16(base + c * CIN + gsw * 8, sw + buf*WB + slot * 16);
      }
    } else {
      #pragma unroll
      for (int it = 0; it < 4; ++it) {
        int slot = it * 256 + tid;
        int c = slot >> 3, gsw = (slot & 7) ^ (c & 7);
        int cout = cblk*128 + c;
        short8 v;
        #pragma unroll
        for (int j = 0; j < 8; ++j) {
          int cin = hh*64 + gsw*8 + j;
          v[j] = f2b(wgt[cout*(CIN*KHW) + cin*KHW + tap]);
        }
        *(short8*)(sw + buf*WB + slot * 16) = v;
      }
    }
  };

  const int lane = tid & 63;
  const int wid  = tid >> 6;      // 0..3
  const int wm = wid >> 1;        // 0..1 -> couts [wm*64, +64) of block's 128
  const int wn = wid & 1;         // 0..1 -> rows [wn*4, +4)
  const int l15 = lane & 15;
  const int kgrp = lane >> 4;     // 0..3

  // loop-invariant address bases
  int arow[4];
  #pragma unroll
  for (int mi = 0; mi < 4; ++mi) arow[mi] = (wm*64 + mi*16 + l15) * 128;
  const int l7 = l15 & 7;

  f32x4 acc[4][8] = {};

  stage_x(0);
  stage_w(0, 0, 0);               // stage 0 = (hh0,s0,kw0,kh0) -> tap 0
  __syncthreads();

  int stg = 0;                    // 36 stages: (hh,s,kw,kh)
  for (int hh = 0; hh < 2; ++hh) {
    #pragma unroll
    for (int s = 0; s < 2; ++s) {
      const int g = s*4 + kgrp;
      const int akey = (g ^ l7) << 4;
      #pragma unroll
      for (int kw = 0; kw < 3; ++kw) {
        // ---- 12-frag B-window: rows 4wn..4wn+5, cg {0,1}; imm offsets ----
        const int bkey = (g ^ ((l15 + kw) & 7)) << 4;
        const char* bb0 = sx + (4*wn)*ROWB + (l15 + kw)*128 + bkey;
        const char* bb1 = bb0 + 16*128;
        short8 win[6][2];
        #pragma unroll
        for (int r = 0; r < 6; ++r) {
          win[r][0] = *(const short8*)(bb0 + r*ROWB);
          win[r][1] = *(const short8*)(bb1 + r*ROWB);
        }
        #pragma unroll
        for (int kh = 0; kh < 3; ++kh) {
          {                                   // stage next stage's w
            int ns = stg + 1;
            if (ns < 36) {
              int nhh = ns / 18, t = ns % 18, r9 = t % 9;
              int ntap = (r9 % 3) * 3 + (r9 / 3);   // kh'*3 + kw'
              stage_w(ntap, nhh, ns & 1);
            }
          }
          const char* swb = sw + (stg & 1) * WB;
          short8 a[4];
          #pragma unroll
          for (int mi = 0; mi < 4; ++mi)
            a[mi] = *(const short8*)(swb + akey + arow[mi]);

          __builtin_amdgcn_s_setprio(1);
          #pragma unroll
          for (int mi = 0; mi < 4; ++mi)
            #pragma unroll
            for (int ni = 0; ni < 8; ++ni)
              acc[mi][ni] = __builtin_amdgcn_mfma_f32_16x16x32_bf16(
                  a[mi], win[(ni >> 1) + kh][ni & 1], acc[mi][ni], 0, 0, 0);
          __builtin_amdgcn_s_setprio(0);

          __syncthreads();        // next-w landed; current buf readers done
          ++stg;
        }
      }
    }
    if (hh == 0) {
      stage_x(1);                 // x half-0 readers done (stg-17 barrier)
      __syncthreads();            // x half-1 ready
    }
  }

  // ---- epilogue: C layout col=l15 (px), row=4*kgrp+r (cout) [m89] ----
  float* ob = out + (size_t)b * COUT * (OH*OW);
  #pragma unroll
  for (int ni = 0; ni < 8; ++ni) {
    int oh = h0 + 4*wn + (ni >> 1);
    int ow = w0 + (ni & 1)*16 + l15;
    if (oh < OH && ow < OW) {
      #pragma unroll
      for (int mi = 0; mi < 4; ++mi) {
        #pragma unroll
        for (int r = 0; r < 4; ++r) {
          int cout = cblk*128 + wm*64 + mi*16 + kgrp*4 + r;
          ob[(size_t)cout*(OH*OW) + oh*OW + ow] = acc[mi][ni][r];
        }
      }
    }
  }
}

// one-time weight transpose+cvt: wt[tap][cout][cin] bf16; also zeros the
// 256-B zero page that follows wt in the workspace.
__global__ void wprep(const float* __restrict__ wgt, short* __restrict__ wt,
                      short* __restrict__ zp) {
  int idx = blockIdx.x * 256 + threadIdx.x;
  if (idx < 128) zp[idx] = 0;
  if (idx >= KHW*COUT*CIN) return;
  int khw  = idx / (COUT*CIN);
  int rem  = idx - khw*(COUT*CIN);
  int cout = rem >> 7, cin = rem & 127;
  wt[idx] = f2b(wgt[cout*(CIN*KHW) + cin*KHW + khw]);
}

// one-time x transpose+cvt: xt[b][h][w][cin] bf16, via padded LDS tile.
__global__ __launch_bounds__(256)
void xprep(const float* __restrict__ x, short* __restrict__ xt) {
  __shared__ short lsh[CIN * 113];   // 28928 B
  const int bh = blockIdx.x;
  const int b = bh / H, h = bh - b * H;
  const float* src = x + ((size_t)b * CIN * H + h) * W;
  for (int u = threadIdx.x; u < CIN * W; u += 256) {
    int c = u / W, w = u - c * W;
    lsh[c * 113 + w] = f2b(src[(size_t)c * (H*W) + w]);
  }
  __syncthreads();
  short* dst = xt + (size_t)bh * (W * CIN);
  for (int o = threadIdx.x; o < W * CIN / 8; o += 256) {   // 1792
    int w = o >> 4, s = o & 15;
    short8 v;
    #pragma unroll
    for (int j = 0; j < 8; ++j) v[j] = lsh[(s*8 + j) * 113 + w];
    *(short8*)(dst + o * 8) = v;
  }
}

extern "C" void kernel_launch(void* const* d_in, const int* in_sizes, int n_in,
                              void* d_out, int out_size, void* d_ws, size_t ws_size,
                              hipStream_t stream) {
  const float* x   = (const float*)d_in[0];
  const float* wgt = (const float*)d_in[1];
  float* out = (float*)d_out;
  const size_t wt_bytes = (size_t)(KHW*COUT*CIN) * sizeof(short);   // 589824
  const size_t zp_bytes = 256;
  const size_t xt_bytes = (size_t)32 * H * W * CIN * sizeof(short); // 102.76 MB
  dim3 grid(3584);   // 2 cblk x 4 tw x 14 th x 32 b
  if (ws_size >= wt_bytes + zp_bytes + xt_bytes) {
    short* wt = (short*)d_ws;
    short* zp = (short*)((char*)d_ws + wt_bytes);
    short* xt = (short*)((char*)d_ws + wt_bytes + zp_bytes);
    wprep<<<(KHW*COUT*CIN + 255)/256, 256, 0, stream>>>(wgt, wt, zp);
    xprep<<<32 * H, 256, 0, stream>>>(x, xt);
    conv_main<true, true><<<grid, 256, 0, stream>>>(x, wgt, wt, xt, zp, out);
  } else if (ws_size >= wt_bytes + zp_bytes) {
    short* wt = (short*)d_ws;
    short* zp = (short*)((char*)d_ws + wt_bytes);
    wprep<<<(KHW*COUT*CIN + 255)/256, 256, 0, stream>>>(wgt, wt, zp);
    conv_main<false, true><<<grid, 256, 0, stream>>>(x, wgt, wt, nullptr, zp, out);
  } else {
    conv_main<false, false><<<grid, 256, 0, stream>>>(x, wgt, nullptr, nullptr, nullptr, out);
  }
}

// Round 15
// 369.867 us; speedup vs baseline: 1.4825x; 1.4825x over previous
//
#include <hip/hip_runtime.h>

typedef __attribute__((ext_vector_type(8))) short short8;
typedef __attribute__((ext_vector_type(4))) float f32x4;
typedef unsigned int u32;

#define CIN   128
#define COUT  256
#define H     112
#define W     112
#define OH    110
#define OW    110
#define KHW   9
#define TH    8
#define TW    32
#define IWW   34              // TW+2
#define NPIX  340             // 10*34
#define XB    (NPIX*8*16)     // 43520 B: x half-tile, 2720 16B slots
#define ROWB  (IWW*128)       // 4352: LDS bytes per x row

__device__ __forceinline__ short f2b(float f) {
  unsigned u = __builtin_bit_cast(unsigned, f);
  unsigned r = (u + 0x7FFFu + ((u >> 16) & 1u)) >> 16;  // RNE
  return (short)r;
}

__device__ __forceinline__ void gload16(const void* g, void* l) {
  __builtin_amdgcn_global_load_lds(
      (const __attribute__((address_space(1))) u32*)g,
      (__attribute__((address_space(3))) u32*)l, 16, 0, 0);
}

// x LDS (R13, proven 0-conflict): byte(p,G) = p*128 + ((G ^ (ix&7))<<4),
// ix = p mod 34 (row-invariant key -> kh/row walks are +4352 immediates).
// DMA linear dest; swizzle pre-applied on per-lane GLOBAL source (m173).
// R15: NO w LDS, NO per-stage barriers. A-fragments read global->VGPR from
// wt2[tap][cinGrp(16)][cout(256)][8] (coalesced 256-B segments, L2-resident,
// ~5 MB HBM). Compute loop = free-running stream of {4 global A + 8 ds_read
// B + 32 MFMA} per s-step, fully unrolled -> compiler hoists next-step loads
// under MFMAs (110+ spare VGPRs). Only barriers: x half-switch (2 total).

template<bool XT, bool WT>
__global__ __launch_bounds__(256, 2)
void conv_main(const float* __restrict__ x, const float* __restrict__ wgt,
               const short* __restrict__ wt2, const short* __restrict__ xt,
               const short* __restrict__ zp, float* __restrict__ out) {
  __shared__ __align__(16) char sx[XB];   // 43520 B

  const int tid = threadIdx.x;

  // XCD-chunked bijective swizzle (3584 % 8 == 0)
  const int nb  = gridDim.x;
  const int swz = (blockIdx.x & 7) * (nb >> 3) + (blockIdx.x >> 3);
  const int b    = swz / 112;            // 2 cblk * 4 tw * 14 th
  const int rem  = swz - b * 112;
  const int cblk = rem / 56;
  const int rem2 = rem - cblk * 56;
  const int t_w  = rem2 / 14;
  const int t_h  = rem2 - t_w * 14;
  const int h0 = t_h * TH, w0 = t_w * TW;

  auto stage_x = [&](int hh) {
    if (XT) {
      const short* xtb = xt + (size_t)b * (H*W*CIN);
      #pragma unroll
      for (int it = 0; it < 11; ++it) {
        int u = it*256 + tid;            // slot index, 2720 total
        if (u < 8*NPIX) {                // prefix-masked tail only: safe
          int p = u >> 3;                // pixel 0..339
          int iy = p / IWW, ix = p - iy * IWW;
          int Geff = (u & 7) ^ (ix & 7); // pre-swizzled source fragment
          int gy = h0 + iy, gx = w0 + ix;
          const short* src = (gy < H && gx < W)
              ? xtb + ((size_t)gy*W + gx)*CIN + hh*64 + Geff*8
              : zp;                      // OOB -> zero page (per-lane src ok)
          gload16(src, sx + u*16);
        }
      }
    } else {
      const float* xh = x + (size_t)b * CIN * (H*W) + (size_t)(hh*64) * (H*W);
      for (int u = tid; u < 8 * NPIX; u += 256) {
        int G = u / NPIX, p = u - G * NPIX;
        int iy = p / IWW, ix = p - iy * IWW;
        int gy = h0 + iy, gx = w0 + ix;
        short8 v = {0,0,0,0,0,0,0,0};
        if (gy < H && gx < W) {
          const float* s = xh + (size_t)(G*8) * (H*W) + gy * W + gx;
          #pragma unroll
          for (int j = 0; j < 8; ++j) v[j] = f2b(s[j * (H*W)]);
        }
        *(short8*)(sx + p*128 + ((G ^ (ix & 7)) << 4)) = v;
      }
    }
  };

  const int lane = tid & 63;
  const int wid  = tid >> 6;      // 0..3
  const int wm = wid >> 1;        // 0..1 -> couts [wm*64, +64) of block's 128
  const int wn = wid & 1;         // 0..1 -> rows [wn*4, +4)
  const int l15 = lane & 15;
  const int kgrp = lane >> 4;     // 0..3

  // per-lane A base offset (shorts): cout = cblk*128 + wm*64 + l15
  const int acout8 = (cblk*128 + wm*64 + l15) * 8;

  f32x4 acc[4][8] = {};

  stage_x(0);
  __syncthreads();

  #pragma unroll
  for (int hh = 0; hh < 2; ++hh) {
    if (hh == 1) {
      __syncthreads();            // all waves done reading x half-0
      stage_x(1);
      __syncthreads();            // x half-1 DMA drained
    }
    #pragma unroll
    for (int tap = 0; tap < 9; ++tap) {
      const int kh = tap / 3, kw = tap - (tap/3)*3;
      #pragma unroll
      for (int s = 0; s < 2; ++s) {
        const int g = s*4 + kgrp;
        // ---- A: 4 coalesced global loads (256-B segments, imm offsets) ----
        short8 a[4];
        if (WT) {
          const short* ap = wt2 + ((size_t)(tap*16 + hh*8) + g) * 2048 + acout8;
          #pragma unroll
          for (int mi = 0; mi < 4; ++mi)
            a[mi] = *(const short8*)(ap + mi*128);   // +mi*16 couts = 256 B
        } else {
          #pragma unroll
          for (int mi = 0; mi < 4; ++mi) {
            int cout = cblk*128 + wm*64 + mi*16 + l15;
            #pragma unroll
            for (int j = 0; j < 8; ++j) {
              int cin = hh*64 + g*8 + j;
              a[mi][j] = f2b(wgt[cout*(CIN*KHW) + cin*KHW + tap]);
            }
          }
        }
        // ---- B: 8 ds_read_b128, base + r*4352 immediates (R13) ----
        const int bkey = (g ^ ((l15 + kw) & 7)) << 4;
        const char* bb0 = sx + (4*wn + kh)*ROWB + (l15 + kw)*128 + bkey;
        const char* bb1 = bb0 + 16*128;
        short8 bf[8];
        #pragma unroll
        for (int r = 0; r < 4; ++r) {
          bf[2*r]   = *(const short8*)(bb0 + r*ROWB);
          bf[2*r+1] = *(const short8*)(bb1 + r*ROWB);
        }
        __builtin_amdgcn_s_setprio(1);
        #pragma unroll
        for (int mi = 0; mi < 4; ++mi)
          #pragma unroll
          for (int ni = 0; ni < 8; ++ni)
            acc[mi][ni] = __builtin_amdgcn_mfma_f32_16x16x32_bf16(
                a[mi], bf[ni], acc[mi][ni], 0, 0, 0);
        __builtin_amdgcn_s_setprio(0);
      }
    }
  }

  // ---- epilogue: C layout col=l15 (px), row=4*kgrp+r (cout) [m89] ----
  float* ob = out + (size_t)b * COUT * (OH*OW);
  #pragma unroll
  for (int ni = 0; ni < 8; ++ni) {
    int oh = h0 + 4*wn + (ni >> 1);
    int ow = w0 + (ni & 1)*16 + l15;
    if (oh < OH && ow < OW) {
      #pragma unroll
      for (int mi = 0; mi < 4; ++mi) {
        #pragma unroll
        for (int r = 0; r < 4; ++r) {
          int cout = cblk*128 + wm*64 + mi*16 + kgrp*4 + r;
          ob[(size_t)cout*(OH*OW) + oh*OW + ow] = acc[mi][ni][r];
        }
      }
    }
  }
}

// one-time weight transpose+cvt: wt2[tap][cinGrp(16)][cout(256)][8] bf16;
// also zeros the 256-B zero page that follows wt2 in the workspace.
__global__ void wprep(const float* __restrict__ wgt, short* __restrict__ wt2,
                      short* __restrict__ zp) {
  int idx = blockIdx.x * 256 + threadIdx.x;   // over 9*16*256 chunks
  if (idx < 128) zp[idx] = 0;
  if (idx >= KHW*16*COUT) return;
  int tap  = idx / (16*COUT);
  int rem  = idx - tap*(16*COUT);
  int G    = rem >> 8, cout = rem & 255;
  short8 v;
  #pragma unroll
  for (int j = 0; j < 8; ++j)
    v[j] = f2b(wgt[cout*(CIN*KHW) + (G*8 + j)*KHW + tap]);
  *(short8*)(wt2 + (size_t)idx * 8) = v;
}

// one-time x transpose+cvt: xt[b][h][w][cin] bf16, via padded LDS tile.
__global__ __launch_bounds__(256)
void xprep(const float* __restrict__ x, short* __restrict__ xt) {
  __shared__ short lsh[CIN * 113];   // 28928 B
  const int bh = blockIdx.x;
  const int b = bh / H, h = bh - b * H;
  const float* src = x + ((size_t)b * CIN * H + h) * W;
  for (int u = threadIdx.x; u < CIN * W; u += 256) {
    int c = u / W, w = u - c * W;
    lsh[c * 113 + w] = f2b(src[(size_t)c * (H*W) + w]);
  }
  __syncthreads();
  short* dst = xt + (size_t)bh * (W * CIN);
  for (int o = threadIdx.x; o < W * CIN / 8; o += 256) {   // 1792
    int w = o >> 4, s = o & 15;
    short8 v;
    #pragma unroll
    for (int j = 0; j < 8; ++j) v[j] = lsh[(s*8 + j) * 113 + w];
    *(short8*)(dst + o * 8) = v;
  }
}

extern "C" void kernel_launch(void* const* d_in, const int* in_sizes, int n_in,
                              void* d_out, int out_size, void* d_ws, size_t ws_size,
                              hipStream_t stream) {
  const float* x   = (const float*)d_in[0];
  const float* wgt = (const float*)d_in[1];
  float* out = (float*)d_out;
  const size_t wt_bytes = (size_t)(KHW*COUT*CIN) * sizeof(short);   // 589824
  const size_t zp_bytes = 256;
  const size_t xt_bytes = (size_t)32 * H * W * CIN * sizeof(short); // 102.76 MB
  dim3 grid(3584);   // 2 cblk x 4 tw x 14 th x 32 b
  if (ws_size >= wt_bytes + zp_bytes + xt_bytes) {
    short* wt2 = (short*)d_ws;
    short* zp  = (short*)((char*)d_ws + wt_bytes);
    short* xt  = (short*)((char*)d_ws + wt_bytes + zp_bytes);
    wprep<<<(KHW*16*COUT + 255)/256, 256, 0, stream>>>(wgt, wt2, zp);
    xprep<<<32 * H, 256, 0, stream>>>(x, xt);
    conv_main<true, true><<<grid, 256, 0, stream>>>(x, wgt, wt2, xt, zp, out);
  } else if (ws_size >= wt_bytes + zp_bytes) {
    short* wt2 = (short*)d_ws;
    short* zp  = (short*)((char*)d_ws + wt_bytes);
    wprep<<<(KHW*16*COUT + 255)/256, 256, 0, stream>>>(wgt, wt2, zp);
    conv_main<false, true><<<grid, 256, 0, stream>>>(x, wgt, wt2, nullptr, zp, out);
  } else {
    conv_main<false, false><<<grid, 256, 0, stream>>>(x, wgt, nullptr, nullptr, nullptr, out);
  }
}

// Round 16
// 338.881 us; speedup vs baseline: 1.6180x; 1.0914x over previous
//
#include <hip/hip_runtime.h>

typedef __attribute__((ext_vector_type(8))) short short8;
typedef __attribute__((ext_vector_type(4))) float f32x4;
typedef unsigned int u32;

#define CIN   128
#define COUT  256
#define H     112
#define W     112
#define OH    110
#define OW    110
#define KHW   9
#define TH    8
#define TW    32
#define IWW   34              // TW+2
#define NPIX  340             // 10*34
#define XB    (NPIX*8*16)     // 43520 B: x half-tile, 2720 16B slots
#define WB    16384           // w tap-half: 128 cout * 8 slots * 16B
#define ROWB  (IWW*128)       // 4352: LDS bytes per x row

__device__ __forceinline__ short f2b(float f) {
  unsigned u = __builtin_bit_cast(unsigned, f);
  unsigned r = (u + 0x7FFFu + ((u >> 16) & 1u)) >> 16;  // RNE
  return (short)r;
}

__device__ __forceinline__ void gload16(const void* g, void* l) {
  __builtin_amdgcn_global_load_lds(
      (const __attribute__((address_space(1))) u32*)g,
      (__attribute__((address_space(3))) u32*)l, 16, 0, 0);
}

// R16 = R13 (best: 256us, 0 conflicts, no spill) + anti-phase startup skew.
// Theory: the 2 co-resident blocks sit in a stable IN-PHASE equilibrium
// (reads contend, then MFMAs contend; period = sum = 5160 cyc/tap, 6%
// overlap measured). Anti-phase is also stable (period = max = 2700).
// A one-time half-period sleep for dispatch-slot-1 blocks (i, i+256 pair
// under XCD-round-robin + breadth-first fill) kicks into anti-phase.
// x LDS (R13): byte(p,G) = p*128 + ((G ^ (ix&7))<<4), ix=p%34 (row-invariant
// key -> kh/row walks are +4352 immediates). DMA linear dest; swizzle
// pre-applied on per-lane GLOBAL source (m173). w LDS: c*128+((G^(c&7))<<4).

template<bool XT, bool WT>
__global__ __launch_bounds__(256, 2)
void conv_main(const float* __restrict__ x, const float* __restrict__ wgt,
               const short* __restrict__ wt, const short* __restrict__ xt,
               const short* __restrict__ zp, float* __restrict__ out) {
  __shared__ __align__(16) char smem[XB + 2*WB];   // 76288 B -> 2 blocks/CU
  char* sx = smem;
  char* sw = smem + XB;

  const int tid = threadIdx.x;

  // anti-phase kick: ~1344 cyc = half of the 2700-cyc anti-phase tap period
  if (blockIdx.x & 256) __builtin_amdgcn_s_sleep(21);

  // XCD-chunked bijective swizzle (3584 % 8 == 0)
  const int nb  = gridDim.x;
  const int swz = (blockIdx.x & 7) * (nb >> 3) + (blockIdx.x >> 3);
  const int b    = swz / 112;            // 2 cblk * 4 tw * 14 th
  const int rem  = swz - b * 112;
  const int cblk = rem / 56;
  const int rem2 = rem - cblk * 56;
  const int t_w  = rem2 / 14;
  const int t_h  = rem2 - t_w * 14;
  const int h0 = t_h * TH, w0 = t_w * TW;

  auto stage_x = [&](int hh) {
    if (XT) {
      const short* xtb = xt + (size_t)b * (H*W*CIN);
      #pragma unroll
      for (int it = 0; it < 11; ++it) {
        int u = it*256 + tid;            // slot index, 2720 total
        if (u < 8*NPIX) {                // prefix-masked tail only: safe
          int p = u >> 3;                // pixel 0..339
          int iy = p / IWW, ix = p - iy * IWW;
          int Geff = (u & 7) ^ (ix & 7); // pre-swizzled source fragment
          int gy = h0 + iy, gx = w0 + ix;
          const short* src = (gy < H && gx < W)
              ? xtb + ((size_t)gy*W + gx)*CIN + hh*64 + Geff*8
              : zp;                      // OOB -> zero page (per-lane src ok)
          gload16(src, sx + u*16);
        }
      }
    } else {
      const float* xh = x + (size_t)b * CIN * (H*W) + (size_t)(hh*64) * (H*W);
      for (int u = tid; u < 8 * NPIX; u += 256) {
        int G = u / NPIX, p = u - G * NPIX;
        int iy = p / IWW, ix = p - iy * IWW;
        int gy = h0 + iy, gx = w0 + ix;
        short8 v = {0,0,0,0,0,0,0,0};
        if (gy < H && gx < W) {
          const float* s = xh + (size_t)(G*8) * (H*W) + gy * W + gx;
          #pragma unroll
          for (int j = 0; j < 8; ++j) v[j] = f2b(s[j * (H*W)]);
        }
        *(short8*)(sx + p*128 + ((G ^ (ix & 7)) << 4)) = v;
      }
    }
  };

  auto stage_w = [&](int st, int buf) {
    int hh = st / 9, tap = st - hh * 9;
    if (WT) {
      const short* base = wt + (size_t)tap * (COUT*CIN)
                             + (size_t)(cblk*128) * CIN + hh * 64;
      #pragma unroll
      for (int it = 0; it < 4; ++it) {
        int slot = it * 256 + tid;            // 1024 slots of 16B
        int c = slot >> 3, gsw = (slot & 7) ^ (c & 7);
        gload16(base + c * CIN + gsw * 8, sw + buf*WB + slot * 16);
      }
    } else {
      #pragma unroll
      for (int it = 0; it < 4; ++it) {
        int slot = it * 256 + tid;
        int c = slot >> 3, gsw = (slot & 7) ^ (c & 7);
        int cout = cblk*128 + c;
        short8 v;
        #pragma unroll
        for (int j = 0; j < 8; ++j) {
          int cin = hh*64 + gsw*8 + j;
          v[j] = f2b(wgt[cout*(CIN*KHW) + cin*KHW + tap]);
        }
        *(short8*)(sw + buf*WB + slot * 16) = v;
      }
    }
  };

  const int lane = tid & 63;
  const int wid  = tid >> 6;      // 0..3
  const int wm = wid >> 1;        // 0..1 -> couts [wm*64, +64) of block's 128
  const int wn = wid & 1;         // 0..1 -> rows [wn*4, +4)
  const int l15 = lane & 15;
  const int kgrp = lane >> 4;     // 0..3

  // loop-invariant address bases
  int arow[4];
  #pragma unroll
  for (int mi = 0; mi < 4; ++mi) arow[mi] = (wm*64 + mi*16 + l15) * 128;
  const int l7 = l15 & 7;

  f32x4 acc[4][8] = {};

  stage_x(0);
  stage_w(0, 0);
  __syncthreads();

  for (int st = 0; st < 18; ++st) {          // 2 cin-halves x 9 taps
    const int tap = st % 9;
    const int kh = tap / 3, kw = tap - (tap/3)*3;
    const char* swb = sw + (st & 1) * WB;
    const int brow = (4*wn + kh) * ROWB;     // B row base (bytes)

    #pragma unroll
    for (int s = 0; s < 2; ++s) {            // two K=32 steps over 64 cins
      const int g = s*4 + kgrp;
      const int akey = (g ^ l7) << 4;
      const int bkey = (g ^ ((l15 + kw) & 7)) << 4;
      const char* ab = swb + akey;
      const char* bb0 = sx + brow + (l15 + kw)*128 + bkey;   // cg=0
      const char* bb1 = bb0 + 16*128;                        // cg=1

      short8 a[4];
      #pragma unroll
      for (int mi = 0; mi < 4; ++mi)
        a[mi] = *(const short8*)(ab + arow[mi]);
      short8 bf[8];
      #pragma unroll
      for (int r = 0; r < 4; ++r) {          // all offsets = imm r*4352
        bf[2*r]   = *(const short8*)(bb0 + r*ROWB);
        bf[2*r+1] = *(const short8*)(bb1 + r*ROWB);
      }

      if (s == 0 && st + 1 < 18)             // issue w-DMA off critical path
        stage_w(st + 1, (st + 1) & 1);

      __builtin_amdgcn_s_setprio(1);
      #pragma unroll
      for (int mi = 0; mi < 4; ++mi)
        #pragma unroll
        for (int ni = 0; ni < 8; ++ni)
          acc[mi][ni] = __builtin_amdgcn_mfma_f32_16x16x32_bf16(a[mi], bf[ni], acc[mi][ni], 0, 0, 0);
      __builtin_amdgcn_s_setprio(0);
    }

    if (st == 8) {
      __syncthreads();      // x half-0 readers done; w(9) DMA drained here
      stage_x(1);
      __syncthreads();      // drains x half-1 DMA
    } else {
      __syncthreads();
    }
  }

  // ---- epilogue: C layout col=l15 (px), row=4*kgrp+r (cout) [m89] ----
  float* ob = out + (size_t)b * COUT * (OH*OW);
  #pragma unroll
  for (int ni = 0; ni < 8; ++ni) {
    int oh = h0 + 4*wn + (ni >> 1);
    int ow = w0 + (ni & 1)*16 + l15;
    if (oh < OH && ow < OW) {
      #pragma unroll
      for (int mi = 0; mi < 4; ++mi) {
        #pragma unroll
        for (int r = 0; r < 4; ++r) {
          int cout = cblk*128 + wm*64 + mi*16 + kgrp*4 + r;
          ob[(size_t)cout*(OH*OW) + oh*OW + ow] = acc[mi][ni][r];
        }
      }
    }
  }
}

// one-time weight transpose+cvt: wt[tap][cout][cin] bf16; also zeros the
// 256-B zero page that follows wt in the workspace.
__global__ void wprep(const float* __restrict__ wgt, short* __restrict__ wt,
                      short* __restrict__ zp) {
  int idx = blockIdx.x * 256 + threadIdx.x;
  if (idx < 128) zp[idx] = 0;
  if (idx >= KHW*COUT*CIN) return;
  int khw  = idx / (COUT*CIN);
  int rem  = idx - khw*(COUT*CIN);
  int cout = rem >> 7, cin = rem & 127;
  wt[idx] = f2b(wgt[cout*(CIN*KHW) + cin*KHW + khw]);
}

// one-time x transpose+cvt: xt[b][h][w][cin] bf16, via padded LDS tile.
__global__ __launch_bounds__(256)
void xprep(const float* __restrict__ x, short* __restrict__ xt) {
  __shared__ short lsh[CIN * 113];   // 28928 B
  const int bh = blockIdx.x;
  const int b = bh / H, h = bh - b * H;
  const float* src = x + ((size_t)b * CIN * H + h) * W;
  for (int u = threadIdx.x; u < CIN * W; u += 256) {
    int c = u / W, w = u - c * W;
    lsh[c * 113 + w] = f2b(src[(size_t)c * (H*W) + w]);
  }
  __syncthreads();
  short* dst = xt + (size_t)bh * (W * CIN);
  for (int o = threadIdx.x; o < W * CIN / 8; o += 256) {   // 1792
    int w = o >> 4, s = o & 15;
    short8 v;
    #pragma unroll
    for (int j = 0; j < 8; ++j) v[j] = lsh[(s*8 + j) * 113 + w];
    *(short8*)(dst + o * 8) = v;
  }
}

extern "C" void kernel_launch(void* const* d_in, const int* in_sizes, int n_in,
                              void* d_out, int out_size, void* d_ws, size_t ws_size,
                              hipStream_t stream) {
  const float* x   = (const float*)d_in[0];
  const float* wgt = (const float*)d_in[1];
  float* out = (float*)d_out;
  const size_t wt_bytes = (size_t)(KHW*COUT*CIN) * sizeof(short);   // 589824
  const size_t zp_bytes = 256;
  const size_t xt_bytes = (size_t)32 * H * W * CIN * sizeof(short); // 102.76 MB
  dim3 grid(3584);   // 2 cblk x 4 tw x 14 th x 32 b
  if (ws_size >= wt_bytes + zp_bytes + xt_bytes) {
    short* wt = (short*)d_ws;
    short* zp = (short*)((char*)d_ws + wt_bytes);
    short* xt = (short*)((char*)d_ws + wt_bytes + zp_bytes);
    wprep<<<(KHW*COUT*CIN + 255)/256, 256, 0, stream>>>(wgt, wt, zp);
    xprep<<<32 * H, 256, 0, stream>>>(x, xt);
    conv_main<true, true><<<grid, 256, 0, stream>>>(x, wgt, wt, xt, zp, out);
  } else if (ws_size >= wt_bytes + zp_bytes) {
    short* wt = (short*)d_ws;
    short* zp = (short*)((char*)d_ws + wt_bytes);
    wprep<<<(KHW*COUT*CIN + 255)/256, 256, 0, stream>>>(wgt, wt, zp);
    conv_main<false, true><<<grid, 256, 0, stream>>>(x, wgt, wt, nullptr, zp, out);
  } else {
    conv_main<false, false><<<grid, 256, 0, stream>>>(x, wgt, nullptr, nullptr, nullptr, out);
  }
}